// Round 9
// baseline (1238.816 us; speedup 1.0000x reference)
//
#include <hip/hip_runtime.h>
#include <hip/hip_bf16.h>

typedef unsigned short u16;
typedef __bf16 bf16x8 __attribute__((ext_vector_type(8)));
typedef float f32x4 __attribute__((ext_vector_type(4)));

#define HH 56
#define WW 56
#define DIM 384
#define NTOK 100352   // 32*3136
#define NWIN 2048     // 32*64
#define NN 49

__device__ __forceinline__ u16 f2bf(float f) {
    __hip_bfloat16 h = __float2bfloat16(f);
    return *reinterpret_cast<u16*>(&h);
}
__device__ __forceinline__ float bf2f(u16 u) {
    union { unsigned int i; float f; } c; c.i = ((unsigned int)u) << 16; return c.f;
}

// exact-GELU: gelu(x) = 0.5*x*(1+erf(x/sqrt2)), erf via A&S 7.1.26 (max err 1.5e-7)
__device__ __forceinline__ float fast_gelu(float x) {
    float au = fabsf(x) * 0.70710678118654752f;
    float t = __builtin_amdgcn_rcpf(fmaf(0.3275911f, au, 1.0f));
    float p = fmaf(t, 1.061405429f, -1.453152027f);
    p = fmaf(t, p, 1.421413741f);
    p = fmaf(t, p, -0.284496736f);
    p = fmaf(t, p, 0.254829592f);
    p = p * t;
    float e = __expf(-au * au);
    float erfau = fmaf(-p, e, 1.0f);
    float erfx = __builtin_copysignf(erfau, x);
    return 0.5f * x * (1.0f + erfx);
}

#define GLD_LDS(gp, lp) __builtin_amdgcn_global_load_lds( \
    (const __attribute__((address_space(1))) void*)(gp), \
    (__attribute__((address_space(3))) void*)(lp), 16, 0, 0)

// ---------------- weight transpose + cast: in (K,N) f32 -> out (N,K) bf16 ----
__global__ void castT(const float* __restrict__ in, u16* __restrict__ out, int K, int N) {
    int i = blockIdx.x * 256 + threadIdx.x;
    if (i < N * K) {
        int n = i / K, kk = i - n * K;
        out[i] = f2bf(in[(size_t)kk * N + n]);
    }
}

// ---------------- bias table: Tb[ty][head][q][kk] = rel_bias + mask (+pad) ---
__global__ void bias_kernel(const float* __restrict__ rel_bias, float* __restrict__ Tb) {
    int ty = blockIdx.x / 12, h = blockIdx.x - ty * 12;
    for (int i = threadIdx.x; i < 4096; i += 256) {
        int q = i >> 6, kk = i & 63;
        float v;
        if (kk >= 49) v = -1e30f;
        else if (q >= 49) v = 0.f;
        else {
            int rn = q / 7, cn = q - rn * 7;
            int rm = kk / 7, cm = kk - rm * 7;
            float rb = rel_bias[((rn - rm + 6) * 13 + (cn - cm + 6)) * 12 + h];
            int h0 = (ty >> 1) ? 49 : 0;
            int w0 = (ty & 1) ? 49 : 0;
            int hn = h0 + rn, hm = h0 + rm, wn = w0 + cn, wm = w0 + cm;
            int regn = (hn < 49 ? 0 : (hn < 53 ? 1 : 2)) * 3 + (wn < 49 ? 0 : (wn < 53 ? 1 : 2));
            int regm = (hm < 49 ? 0 : (hm < 53 ? 1 : 2)) * 3 + (wm < 49 ? 0 : (wm < 53 ? 1 : 2));
            v = rb + ((regn == regm) ? 0.f : -10000.f);
        }
        Tb[(size_t)blockIdx.x * 4096 + i] = v;
    }
}

// ---------------- LayerNorm (one wave per token). WIN_MAP: write to windowed pos
template<bool WIN_MAP>
__global__ __launch_bounds__(256) void ln_kernel(
    const float* __restrict__ x, const float* __restrict__ w, const float* __restrict__ b,
    u16* __restrict__ out)
{
    int token = blockIdx.x * 4 + (threadIdx.x >> 6);
    int lane = threadIdx.x & 63;
    const float* row = x + (size_t)token * DIM;
    float v[6]; float sum = 0.f, sq = 0.f;
#pragma unroll
    for (int j = 0; j < 3; j++) {
        float2 p = *(const float2*)(row + lane * 2 + j * 128);
        v[2*j] = p.x; v[2*j+1] = p.y;
        sum += p.x + p.y; sq += p.x * p.x + p.y * p.y;
    }
#pragma unroll
    for (int off = 32; off; off >>= 1) { sum += __shfl_xor(sum, off); sq += __shfl_xor(sq, off); }
    float mu = sum * (1.f / DIM);
    float rstd = rsqrtf(sq * (1.f / DIM) - mu * mu + 1e-5f);
    size_t obase;
    if (WIN_MAP) {
        int b_ = token / 3136, hw = token - b_ * 3136;
        int h = hw / WW, wc_ = hw - h * WW;
        int hr = h - 3; if (hr < 0) hr += HH;
        int wr = wc_ - 3; if (wr < 0) wr += WW;
        int win = b_ * 64 + (hr / 7) * 8 + (wr / 7);
        int n = (hr % 7) * 7 + (wr % 7);
        obase = ((size_t)win * NN + n) * DIM;
    } else {
        obase = (size_t)token * DIM;
    }
#pragma unroll
    for (int j = 0; j < 3; j++) {
        int c = lane * 2 + j * 128;
        float a0 = (v[2*j]   - mu) * rstd * w[c]   + b[c];
        float a1 = (v[2*j+1] - mu) * rstd * w[c+1] + b[c+1];
        unsigned int pair = (unsigned int)f2bf(a0) | ((unsigned int)f2bf(a1) << 16);
        *(unsigned int*)(out + obase + c) = pair;
    }
}

// ---------------- GEMM: C = A(MxK) * Bt(NxK)^T + bias, bf16 in, fp32 acc -----
// A: 3-buffer counted gld_lds pipeline (24 KB LDS). B: L2-resident panel ->
// per-lane asm global_load_dwordx4 direct to regs, double-buffered one K-step
// ahead (no LDS, no barrier payload). Exact counted vmcnt (in-order retire).
template<int EPI, int NT>
__global__ __launch_bounds__(256, 4) void gemm_kernel(
    const u16* __restrict__ A, const u16* __restrict__ Bt,
    const float* __restrict__ bias, const float* __restrict__ resid,
    void* __restrict__ outp, int N, int BNT)
{
    const int K = NT * 32;
    __shared__ u16 sA[3][4096];
    const int tid = threadIdx.x;
    const int lane = tid & 63;
    const int wave = tid >> 6;
    const int wr = wave >> 1, wc = wave & 1;

    // XCD-bijective swizzle (nb % 8 == 0 for all our grids), bn innermost
    const int q8 = gridDim.x >> 3;
    const int wg = (blockIdx.x & 7) * q8 + (blockIdx.x >> 3);
    const int bm = wg / BNT, bn = wg - bm * BNT;

    f32x4 acc[4][4] = {};

    // A staging: thread -> row r0 = tid>>2 (within 64-row half), LDS slot tid&3.
    // global k-group pre-swizzled so lds[row][slot] holds kg = slot^(row&3)^((row>>2)&3)
    const int r0 = tid >> 2;
    const int sg = (tid & 3) ^ (r0 & 3) ^ ((r0 >> 2) & 3);
    const u16* Arow0 = A + (size_t)(bm * 128 + r0) * K + sg * 8;
    const u16* Arow1 = Arow0 + (size_t)64 * K;

    const int l15 = lane & 15, g = lane >> 4;
    // B fragment pointers (direct, no swizzle): row = output col, 16B per lane
    const u16* Brow[4];
#pragma unroll
    for (int n = 0; n < 4; n++)
        Brow[n] = Bt + (size_t)(bn * 128 + wc * 64 + n * 16 + l15) * K + g * 8;

#define STAGE_A(t, buf) do { \
        GLD_LDS(Arow0 + (t) * 32, &sA[buf][wave * 512]); \
        GLD_LDS(Arow1 + (t) * 32, &sA[buf][2048 + wave * 512]); \
    } while (0)

#define LOADB(t, arr) do { \
        asm volatile("global_load_dwordx4 %0, %1, off" : "=&v"(arr[0]) : "v"(Brow[0] + (t) * 32) : "memory"); \
        asm volatile("global_load_dwordx4 %0, %1, off" : "=&v"(arr[1]) : "v"(Brow[1] + (t) * 32) : "memory"); \
        asm volatile("global_load_dwordx4 %0, %1, off" : "=&v"(arr[2]) : "v"(Brow[2] + (t) * 32) : "memory"); \
        asm volatile("global_load_dwordx4 %0, %1, off" : "=&v"(arr[3]) : "v"(Brow[3] + (t) * 32) : "memory"); \
    } while (0)

    int4 b0[4], b1[4];
    // prologue: A(0), A(1) staged; B(0) in flight
    STAGE_A(0, 0);
    STAGE_A(1, 1);
    LOADB(0, b0);

    // de-swizzled k-slot for A reads (conflict-free bank spread)
    const int ssr = (g ^ (l15 & 3) ^ ((l15 >> 2) & 3)) * 8;

#pragma unroll
    for (int t = 0; t < NT; t++) {
        const int buf = t % 3;
        // wait A(t) landed: outstanding <= A(t+1):2 + B(t):4 (in-order retire)
        if (t + 1 < NT) asm volatile("s_waitcnt vmcnt(6)" ::: "memory");
        else            asm volatile("s_waitcnt vmcnt(4)" ::: "memory");
        __builtin_amdgcn_s_barrier();          // publish A(t)
        __builtin_amdgcn_sched_barrier(0);
        if (t + 2 < NT) STAGE_A(t + 2, (t + 2) % 3);
        if (t + 1 < NT) { if ((t & 1) == 0) LOADB(t + 1, b1); else LOADB(t + 1, b0); }
        // wait B(t) landed: outstanding <= A(t+2):2 + B(t+1):4
        if (t + 2 < NT)      asm volatile("s_waitcnt vmcnt(6)" ::: "memory");
        else if (t + 1 < NT) asm volatile("s_waitcnt vmcnt(4)" ::: "memory");
        else                 asm volatile("s_waitcnt vmcnt(0)" ::: "memory");
        __builtin_amdgcn_sched_barrier(0);     // rule #18: MFMA must not hoist above wait
        const int4* bc = ((t & 1) == 0) ? b0 : b1;
#pragma unroll
        for (int m = 0; m < 4; m++) {
            int row = wr * 64 + m * 16 + l15;
            bf16x8 af = *(const bf16x8*)&sA[buf][row * 32 + ssr];
#pragma unroll
            for (int n = 0; n < 4; n++) {
                bf16x8 bfr = *(const bf16x8*)&bc[n];
                // swapped operands: D(row = A-row -> l15, col = B-col -> g*4+reg)
                acc[m][n] = __builtin_amdgcn_mfma_f32_16x16x32_bf16(bfr, af, acc[m][n], 0, 0, 0);
            }
        }
    }
#undef STAGE_A
#undef LOADB

    // ---- epilogue: lane holds C[bm*128+wr*64+m*16+l15][bn*128+wc*64+n*16+g*4 + r]
    const int cb0 = bn * 128 + wc * 64 + g * 4;
    float4 bias4[4];
#pragma unroll
    for (int n = 0; n < 4; n++) bias4[n] = *(const float4*)(bias + cb0 + n * 16);

#pragma unroll
    for (int m = 0; m < 4; m++) {
        int row = bm * 128 + wr * 64 + m * 16 + l15;
        size_t obase;
        if (EPI == 1) {
            int win = row / NN, n = row - win * NN;
            int b_ = win >> 6, wi = win & 63;
            int hr = (wi >> 3) * 7 + n / 7;
            int wcl = (wi & 7) * 7 + n % 7;
            int hf = hr + 3; if (hf >= HH) hf -= HH;
            int wf = wcl + 3; if (wf >= WW) wf -= WW;
            obase = ((size_t)b_ * 3136 + hf * WW + wf) * DIM;
        } else {
            obase = (size_t)row * N;
        }
#pragma unroll
        for (int n = 0; n < 4; n++) {
            int col = cb0 + n * 16;
            float v0 = acc[m][n][0] + bias4[n].x;
            float v1 = acc[m][n][1] + bias4[n].y;
            float v2 = acc[m][n][2] + bias4[n].z;
            float v3 = acc[m][n][3] + bias4[n].w;
            if (EPI == 0 || EPI == 2) {
                if (EPI == 2) { v0 = fast_gelu(v0); v1 = fast_gelu(v1); v2 = fast_gelu(v2); v3 = fast_gelu(v3); }
                uint2 pk;
                pk.x = (unsigned int)f2bf(v0) | ((unsigned int)f2bf(v1) << 16);
                pk.y = (unsigned int)f2bf(v2) | ((unsigned int)f2bf(v3) << 16);
                *(uint2*)((u16*)outp + obase + col) = pk;
            } else {
                const float4 rs = *(const float4*)(resid + obase + col);
                float4 o;
                o.x = v0 + rs.x; o.y = v1 + rs.y; o.z = v2 + rs.z; o.w = v3 + rs.w;
                *(float4*)((float*)outp + obase + col) = o;
            }
        }
    }
}

// ---------------- MFMA windowed attention: one wave per (window, head) -------
__global__ __launch_bounds__(256) void attn_kernel(
    const u16* __restrict__ qkv, const float* __restrict__ Tb,
    u16* __restrict__ attn_out)
{
    // per-wave LDS: Vt[32][72] + P[64][72] (u16), 13824 B/wave
    __shared__ u16 smem[4][6912];
    const int win = blockIdx.x;
    const int wave = threadIdx.x >> 6;
    const int lane = threadIdx.x & 63;
    const int head = blockIdx.y * 4 + wave;
    const int l15 = lane & 15, g = lane >> 4;

    u16* Vt = smem[wave];
    u16* P  = Vt + 2304;

    const u16* qkvw = qkv + (size_t)win * NN * 1152 + head * 32;

    // ---- stage V transposed (zero-pad rows >= 49) ----
    {
        int m = lane;
        bool real = m < NN;
        const u16* vrow = qkvw + (size_t)(real ? m : 0) * 1152 + 768;
        int4 z = {0,0,0,0};
        int4 c0 = real ? *(const int4*)(vrow)      : z;
        int4 c1 = real ? *(const int4*)(vrow + 8)  : z;
        int4 c2 = real ? *(const int4*)(vrow + 16) : z;
        int4 c3 = real ? *(const int4*)(vrow + 24) : z;
        u16 vals[32];
        *(int4*)&vals[0]  = c0; *(int4*)&vals[8]  = c1;
        *(int4*)&vals[16] = c2; *(int4*)&vals[24] = c3;
#pragma unroll
        for (int d = 0; d < 32; d++) Vt[d * 72 + m] = vals[d];
    }

    // ---- S^T = K * Q^T via MFMA (rows clamped to 48: no garbage) ----
    bf16x8 kf[4], qf[4];
#pragma unroll
    for (int t = 0; t < 4; t++) {
        int row = t * 16 + l15; if (row > 48) row = 48;
        const u16* base = qkvw + (size_t)row * 1152 + g * 8;
        kf[t] = *(const bf16x8*)(base + 384);
        qf[t] = *(const bf16x8*)(base);
    }
    f32x4 s[4][4];   // [key-tile mt][query-tile nt]
#pragma unroll
    for (int mt = 0; mt < 4; mt++)
#pragma unroll
        for (int nt = 0; nt < 4; nt++) {
            f32x4 zero = {};
            s[mt][nt] = __builtin_amdgcn_mfma_f32_16x16x32_bf16(kf[mt], qf[nt], zero, 0, 0, 0);
        }

    // ---- bias + mask + softmax (query = nt*16 + l15, keys in regs) ----
    const int wi = win & 63;
    const int ty = (((wi >> 3) == 7) ? 2 : 0) + (((wi & 7) == 7) ? 1 : 0);
    const float* tbb = Tb + (((size_t)ty * 12 + head) << 12);
    const float SCALE = 0.17677669529663687f;
#pragma unroll
    for (int nt = 0; nt < 4; nt++) {
        int q = nt * 16 + l15;
        const float* trow = tbb + q * 64 + g * 4;
        f32x4 b[4];
#pragma unroll
        for (int mt = 0; mt < 4; mt++) b[mt] = *(const f32x4*)(trow + mt * 16);
        float mx = -3e38f;
#pragma unroll
        for (int mt = 0; mt < 4; mt++)
#pragma unroll
            for (int r = 0; r < 4; r++) {
                float v = s[mt][nt][r] * SCALE + b[mt][r];
                s[mt][nt][r] = v;
                mx = fmaxf(mx, v);
            }
        mx = fmaxf(mx, __shfl_xor(mx, 16));
        mx = fmaxf(mx, __shfl_xor(mx, 32));
        float sum = 0.f;
#pragma unroll
        for (int mt = 0; mt < 4; mt++)
#pragma unroll
            for (int r = 0; r < 4; r++) {
                float e = __expf(s[mt][nt][r] - mx);
                s[mt][nt][r] = e;
                sum += e;
            }
        sum += __shfl_xor(sum, 16);
        sum += __shfl_xor(sum, 32);
        float inv = 1.f / sum;
#pragma unroll
        for (int mt = 0; mt < 4; mt++) {
            unsigned int p01 = (unsigned int)f2bf(s[mt][nt][0] * inv) | ((unsigned int)f2bf(s[mt][nt][1] * inv) << 16);
            unsigned int p23 = (unsigned int)f2bf(s[mt][nt][2] * inv) | ((unsigned int)f2bf(s[mt][nt][3] * inv) << 16);
            uint2 pk; pk.x = p01; pk.y = p23;
            *(uint2*)&P[(unsigned)q * 72 + mt * 16 + g * 4] = pk;
        }
    }

    // ---- O = P * V via MFMA ----
    bf16x8 vf[2][2];
#pragma unroll
    for (int ks = 0; ks < 2; ks++)
#pragma unroll
        for (int dt = 0; dt < 2; dt++)
            vf[ks][dt] = *(const bf16x8*)&Vt[(dt * 16 + l15) * 72 + ks * 32 + g * 8];

    f32x4 o[4][2] = {};
#pragma unroll
    for (int nt = 0; nt < 4; nt++) {
        bf16x8 pf0 = *(const bf16x8*)&P[(nt * 16 + l15) * 72 + g * 8];
        bf16x8 pf1 = *(const bf16x8*)&P[(nt * 16 + l15) * 72 + 32 + g * 8];
#pragma unroll
        for (int dt = 0; dt < 2; dt++) {
            o[nt][dt] = __builtin_amdgcn_mfma_f32_16x16x32_bf16(pf0, vf[0][dt], o[nt][dt], 0, 0, 0);
            o[nt][dt] = __builtin_amdgcn_mfma_f32_16x16x32_bf16(pf1, vf[1][dt], o[nt][dt], 0, 0, 0);
        }
    }

    // ---- write out ----
#pragma unroll
    for (int nt = 0; nt < 4; nt++)
#pragma unroll
        for (int r = 0; r < 4; r++) {
            int q = nt * 16 + 4 * g + r;
            if (q < NN) {
                size_t ob = ((size_t)win * NN + q) * DIM + head * 32;
                attn_out[ob + l15]      = f2bf(o[nt][0][r]);
                attn_out[ob + 16 + l15] = f2bf(o[nt][1][r]);
            }
        }
}

// ---------------- launch ------------------------------------------------------
extern "C" void kernel_launch(void* const* d_in, const int* in_sizes, int n_in,
                              void* d_out, int out_size, void* d_ws, size_t ws_size,
                              hipStream_t stream)
{
    const float* x      = (const float*)d_in[0];
    const float* qkv_w  = (const float*)d_in[1];
    const float* qkv_b  = (const float*)d_in[2];
    const float* proj_w = (const float*)d_in[3];
    const float* proj_b = (const float*)d_in[4];
    const float* rel_b  = (const float*)d_in[5];
    const float* n1w    = (const float*)d_in[6];
    const float* n1b    = (const float*)d_in[7];
    const float* n2w    = (const float*)d_in[8];
    const float* n2b    = (const float*)d_in[9];
    const float* w1     = (const float*)d_in[10];
    const float* b1     = (const float*)d_in[11];
    const float* w2     = (const float*)d_in[12];
    const float* b2     = (const float*)d_in[13];

    char* ws = (char*)d_ws;
    u16* hidden  = (u16*)(ws);                       // 100352x1536 bf16 (MLP hidden)
    u16* qkvbuf  = hidden;                           // 100352x1152 bf16 (aliases hidden)
    float* Tb    = (float*)(ws + 231211008);         // 4x12x64x64 f32 bias table
    u16* wxbuf   = (u16*)(ws + 308281344);           // 100352x384 bf16 (wx / attn_out / ln2)
    u16* qkv_wt  = (u16*)(ws + 385351680);           // 1152x384
    u16* proj_wt = (u16*)(ws + 386236416);           // 384x384
    u16* w1t     = (u16*)(ws + 386531328);           // 1536x384
    u16* w2t     = (u16*)(ws + 387710976);           // 384x1536

    castT<<<(1152*384 + 255) / 256, 256, 0, stream>>>(qkv_w, qkv_wt, 384, 1152);
    castT<<<(384*384  + 255) / 256, 256, 0, stream>>>(proj_w, proj_wt, 384, 384);
    castT<<<(384*1536 + 255) / 256, 256, 0, stream>>>(w1, w1t, 384, 1536);
    castT<<<(1536*384 + 255) / 256, 256, 0, stream>>>(w2, w2t, 1536, 384);
    bias_kernel<<<48, 256, 0, stream>>>(rel_b, Tb);

    // LN1 + roll + window partition
    ln_kernel<true><<<NTOK / 4, 256, 0, stream>>>(x, n1w, n1b, wxbuf);
    // QKV GEMM
    gemm_kernel<0, 12><<<784 * 9, 256, 0, stream>>>(wxbuf, qkv_wt, qkv_b, nullptr, qkvbuf, 1152, 9);
    // attention (overwrites wxbuf with attn output, windowed layout)
    attn_kernel<<<dim3(NWIN, 3), 256, 0, stream>>>(qkvbuf, Tb, wxbuf);
    // proj GEMM + window reverse + roll + residual -> y1 in d_out (f32)
    gemm_kernel<1, 12><<<784 * 3, 256, 0, stream>>>(wxbuf, proj_wt, proj_b, x, d_out, 384, 3);
    // LN2 on y1 -> wxbuf (bf16)
    ln_kernel<false><<<NTOK / 4, 256, 0, stream>>>((const float*)d_out, n2w, n2b, wxbuf);
    // MLP1 + GELU -> hidden
    gemm_kernel<2, 12><<<784 * 12, 256, 0, stream>>>(wxbuf, w1t, b1, nullptr, hidden, 1536, 12);
    // MLP2 + residual(y1) -> d_out (f32)
    gemm_kernel<3, 48><<<784 * 3, 256, 0, stream>>>(hidden, w2t, b2, (const float*)d_out, d_out, 384, 3);
}

// Round 10
// 991.364 us; speedup vs baseline: 1.2496x; 1.2496x over previous
//
#include <hip/hip_runtime.h>
#include <hip/hip_bf16.h>

typedef unsigned short u16;
typedef __bf16 bf16x8 __attribute__((ext_vector_type(8)));
typedef float f32x4 __attribute__((ext_vector_type(4)));

#define HH 56
#define WW 56
#define DIM 384
#define NTOK 100352   // 32*3136
#define NWIN 2048     // 32*64
#define NN 49

__device__ __forceinline__ u16 f2bf(float f) {
    __hip_bfloat16 h = __float2bfloat16(f);
    return *reinterpret_cast<u16*>(&h);
}
__device__ __forceinline__ float bf2f(u16 u) {
    union { unsigned int i; float f; } c; c.i = ((unsigned int)u) << 16; return c.f;
}

// exact-GELU: gelu(x) = 0.5*x*(1+erf(x/sqrt2)), erf via A&S 7.1.26 (max err 1.5e-7)
__device__ __forceinline__ float fast_gelu(float x) {
    float au = fabsf(x) * 0.70710678118654752f;
    float t = __builtin_amdgcn_rcpf(fmaf(0.3275911f, au, 1.0f));
    float p = fmaf(t, 1.061405429f, -1.453152027f);
    p = fmaf(t, p, 1.421413741f);
    p = fmaf(t, p, -0.284496736f);
    p = fmaf(t, p, 0.254829592f);
    p = p * t;
    float e = __expf(-au * au);
    float erfau = fmaf(-p, e, 1.0f);
    float erfx = __builtin_copysignf(erfau, x);
    return 0.5f * x * (1.0f + erfx);
}

#define GLD_LDS(gp, lp) __builtin_amdgcn_global_load_lds( \
    (const __attribute__((address_space(1))) void*)(gp), \
    (__attribute__((address_space(3))) void*)(lp), 16, 0, 0)

// ---------------- weight transpose + cast: in (K,N) f32 -> out (N,K) bf16 ----
__global__ void castT(const float* __restrict__ in, u16* __restrict__ out, int K, int N) {
    int i = blockIdx.x * 256 + threadIdx.x;
    if (i < N * K) {
        int n = i / K, kk = i - n * K;
        out[i] = f2bf(in[(size_t)kk * N + n]);
    }
}

// ---------------- bias table: Tb[ty][head][q][kk] = rel_bias + mask (+pad) ---
__global__ void bias_kernel(const float* __restrict__ rel_bias, float* __restrict__ Tb) {
    int ty = blockIdx.x / 12, h = blockIdx.x - ty * 12;
    for (int i = threadIdx.x; i < 4096; i += 256) {
        int q = i >> 6, kk = i & 63;
        float v;
        if (kk >= 49) v = -1e30f;
        else if (q >= 49) v = 0.f;
        else {
            int rn = q / 7, cn = q - rn * 7;
            int rm = kk / 7, cm = kk - rm * 7;
            float rb = rel_bias[((rn - rm + 6) * 13 + (cn - cm + 6)) * 12 + h];
            int h0 = (ty >> 1) ? 49 : 0;
            int w0 = (ty & 1) ? 49 : 0;
            int hn = h0 + rn, hm = h0 + rm, wn = w0 + cn, wm = w0 + cm;
            int regn = (hn < 49 ? 0 : (hn < 53 ? 1 : 2)) * 3 + (wn < 49 ? 0 : (wn < 53 ? 1 : 2));
            int regm = (hm < 49 ? 0 : (hm < 53 ? 1 : 2)) * 3 + (wm < 49 ? 0 : (wm < 53 ? 1 : 2));
            v = rb + ((regn == regm) ? 0.f : -10000.f);
        }
        Tb[(size_t)blockIdx.x * 4096 + i] = v;
    }
}

// ---------------- LayerNorm (one wave per token), write to windowed pos ------
__global__ __launch_bounds__(256) void ln_kernel(
    const float* __restrict__ x, const float* __restrict__ w, const float* __restrict__ b,
    u16* __restrict__ out)
{
    int token = blockIdx.x * 4 + (threadIdx.x >> 6);
    int lane = threadIdx.x & 63;
    const float* row = x + (size_t)token * DIM;
    float v[6]; float sum = 0.f, sq = 0.f;
#pragma unroll
    for (int j = 0; j < 3; j++) {
        float2 p = *(const float2*)(row + lane * 2 + j * 128);
        v[2*j] = p.x; v[2*j+1] = p.y;
        sum += p.x + p.y; sq += p.x * p.x + p.y * p.y;
    }
#pragma unroll
    for (int off = 32; off; off >>= 1) { sum += __shfl_xor(sum, off); sq += __shfl_xor(sq, off); }
    float mu = sum * (1.f / DIM);
    float rstd = rsqrtf(sq * (1.f / DIM) - mu * mu + 1e-5f);
    int b_ = token / 3136, hw = token - b_ * 3136;
    int h = hw / WW, wc_ = hw - h * WW;
    int hr = h - 3; if (hr < 0) hr += HH;
    int wr = wc_ - 3; if (wr < 0) wr += WW;
    int win = b_ * 64 + (hr / 7) * 8 + (wr / 7);
    int n = (hr % 7) * 7 + (wr % 7);
    size_t obase = ((size_t)win * NN + n) * DIM;
#pragma unroll
    for (int j = 0; j < 3; j++) {
        int c = lane * 2 + j * 128;
        float a0 = (v[2*j]   - mu) * rstd * w[c]   + b[c];
        float a1 = (v[2*j+1] - mu) * rstd * w[c+1] + b[c+1];
        unsigned int pair = (unsigned int)f2bf(a0) | ((unsigned int)f2bf(a1) << 16);
        *(unsigned int*)(out + obase + c) = pair;
    }
}

// ---------------- GEMM (round-5 929us version): 3-buf counted pipeline -------
template<int EPI>
__global__ __launch_bounds__(256, 3) void gemm_kernel(
    const u16* __restrict__ A, const u16* __restrict__ Bt,
    const float* __restrict__ bias, const float* __restrict__ resid,
    void* __restrict__ outp, int N, int K, int BNT)
{
    __shared__ u16 sA[3][4096];
    __shared__ u16 sB[3][4096];
    const int tid = threadIdx.x;
    const int lane = tid & 63;
    const int wave = tid >> 6;
    const int wr = wave >> 1, wc = wave & 1;

    const int q8 = gridDim.x >> 3;
    const int wg = (blockIdx.x & 7) * q8 + (blockIdx.x >> 3);
    const int bm = wg / BNT, bn = wg - bm * BNT;

    f32x4 acc[4][4] = {};

    const int r0 = tid >> 2;
    const int sg = (tid & 3) ^ (r0 & 3) ^ ((r0 >> 2) & 3);
    const u16* Arow0 = A + (size_t)(bm * 128 + r0) * K + sg * 8;
    const u16* Arow1 = Arow0 + (size_t)64 * K;
    const u16* Brow0 = Bt + (size_t)(bn * 128 + r0) * K + sg * 8;
    const u16* Brow1 = Brow0 + (size_t)64 * K;

    const int nt = K >> 5;

#define STAGE(t, buf) do { \
        int kt_ = (t) * 32; \
        GLD_LDS(Arow0 + kt_, &sA[buf][wave * 512]); \
        GLD_LDS(Arow1 + kt_, &sA[buf][2048 + wave * 512]); \
        GLD_LDS(Brow0 + kt_, &sB[buf][wave * 512]); \
        GLD_LDS(Brow1 + kt_, &sB[buf][2048 + wave * 512]); \
    } while (0)

    STAGE(0, 0); STAGE(1, 1);

    const int l15 = lane & 15, g = lane >> 4;
    const int ssr = (g ^ (l15 & 3) ^ ((l15 >> 2) & 3)) * 8;

    int buf = 0;
    for (int t = 0; t < nt; t++) {
        if (t + 1 < nt) asm volatile("s_waitcnt vmcnt(4)" ::: "memory");
        else            asm volatile("s_waitcnt vmcnt(0)" ::: "memory");
        __builtin_amdgcn_s_barrier();
        __builtin_amdgcn_sched_barrier(0);
        if (t + 2 < nt) {
            int nb = buf + 2; if (nb >= 3) nb -= 3;
            STAGE(t + 2, nb);
        }
        bf16x8 af[4], bfr[4];
#pragma unroll
        for (int m = 0; m < 4; m++) {
            int row = wr * 64 + m * 16 + l15;
            af[m] = *(const bf16x8*)&sA[buf][row * 32 + ssr];
        }
#pragma unroll
        for (int n = 0; n < 4; n++) {
            int row = wc * 64 + n * 16 + l15;
            bfr[n] = *(const bf16x8*)&sB[buf][row * 32 + ssr];
        }
#pragma unroll
        for (int m = 0; m < 4; m++)
#pragma unroll
            for (int n = 0; n < 4; n++)
                acc[m][n] = __builtin_amdgcn_mfma_f32_16x16x32_bf16(af[m], bfr[n], acc[m][n], 0, 0, 0);
        buf = buf + 1; if (buf >= 3) buf = 0;
    }
#undef STAGE

    const int col0 = bn * 128 + wc * 64 + l15;
    float bias4[4];
#pragma unroll
    for (int nn = 0; nn < 4; nn++) bias4[nn] = bias[col0 + nn * 16];

#pragma unroll
    for (int m = 0; m < 4; m++) {
#pragma unroll
        for (int r = 0; r < 4; r++) {
            int row = bm * 128 + wr * 64 + m * 16 + (g << 2) + r;
            size_t obase = (size_t)row * N;
#pragma unroll
            for (int nn = 0; nn < 4; nn++) {
                int col = col0 + nn * 16;
                float val = acc[m][nn][r] + bias4[nn];
                if (EPI == 0) {
                    ((u16*)outp)[obase + col] = f2bf(val);
                } else if (EPI == 2) {
                    ((u16*)outp)[obase + col] = f2bf(fast_gelu(val));
                } else {
                    ((float*)outp)[obase + col] = val + resid[obase + col];
                }
            }
        }
    }
}

// ---------------- fused attention + proj + residual + LN2 --------------------
// One block per window. 4 waves x 3 heads. O -> LDS tiles (sA-layout, slot-XOR).
// Proj: A fully LDS-resident (no staging latency), B (proj_wt) L2-resident.
// Epilogue: y1 = proj+bias+resid(x) -> d_out (f32, scattered), LN2 -> wxbuf.
__global__ __launch_bounds__(256) void attn_proj_kernel(
    const u16* __restrict__ qkv, const float* __restrict__ Tb,
    const u16* __restrict__ projw, const float* __restrict__ projb,
    const float* __restrict__ x, const float* __restrict__ n2w,
    const float* __restrict__ n2b, float* __restrict__ y1,
    u16* __restrict__ ln2out)
{
    __shared__ u16 scratch[4][6912];    // per wave: Vt[32][72] + P[64][72]
    __shared__ u16 outT[12 * 2048];     // 12 head-tiles [64][32], slot-XOR layout
    __shared__ float stats[64][2];      // LN2 row sums
    const int win = blockIdx.x;
    const int tid = threadIdx.x;
    const int wave = tid >> 6;
    const int lane = tid & 63;
    const int l15 = lane & 15, g = lane >> 4;

    u16* Vt = scratch[wave];
    u16* P  = Vt + 2304;

    const int wi = win & 63;
    const int ty = (((wi >> 3) == 7) ? 2 : 0) + (((wi & 7) == 7) ? 1 : 0);
    const float SCALE = 0.17677669529663687f;

    // ================= attention phase: 3 heads per wave =================
    for (int hi = 0; hi < 3; hi++) {
        const int head = wave + hi * 4;
        const u16* qkvw = qkv + (size_t)win * NN * 1152 + head * 32;

        // stage V transposed (zero-pad rows >= 49)
        {
            int m = lane;
            bool real = m < NN;
            const u16* vrow = qkvw + (size_t)(real ? m : 0) * 1152 + 768;
            int4 z = {0,0,0,0};
            int4 c0 = real ? *(const int4*)(vrow)      : z;
            int4 c1 = real ? *(const int4*)(vrow + 8)  : z;
            int4 c2 = real ? *(const int4*)(vrow + 16) : z;
            int4 c3 = real ? *(const int4*)(vrow + 24) : z;
            u16 vals[32];
            *(int4*)&vals[0]  = c0; *(int4*)&vals[8]  = c1;
            *(int4*)&vals[16] = c2; *(int4*)&vals[24] = c3;
#pragma unroll
            for (int d = 0; d < 32; d++) Vt[d * 72 + m] = vals[d];
        }

        // S^T = K * Q^T via MFMA (rows clamped to 48)
        bf16x8 kf[4], qf[4];
#pragma unroll
        for (int t = 0; t < 4; t++) {
            int row = t * 16 + l15; if (row > 48) row = 48;
            const u16* base = qkvw + (size_t)row * 1152 + g * 8;
            kf[t] = *(const bf16x8*)(base + 384);
            qf[t] = *(const bf16x8*)(base);
        }
        f32x4 s[4][4];
#pragma unroll
        for (int mt = 0; mt < 4; mt++)
#pragma unroll
            for (int nt = 0; nt < 4; nt++) {
                f32x4 zero = {};
                s[mt][nt] = __builtin_amdgcn_mfma_f32_16x16x32_bf16(kf[mt], qf[nt], zero, 0, 0, 0);
            }

        // bias + mask + softmax
        const float* tbb = Tb + (((size_t)ty * 12 + head) << 12);
#pragma unroll
        for (int nt = 0; nt < 4; nt++) {
            int q = nt * 16 + l15;
            const float* trow = tbb + q * 64 + g * 4;
            f32x4 b[4];
#pragma unroll
            for (int mt = 0; mt < 4; mt++) b[mt] = *(const f32x4*)(trow + mt * 16);
            float mx = -3e38f;
#pragma unroll
            for (int mt = 0; mt < 4; mt++)
#pragma unroll
                for (int r = 0; r < 4; r++) {
                    float v = s[mt][nt][r] * SCALE + b[mt][r];
                    s[mt][nt][r] = v;
                    mx = fmaxf(mx, v);
                }
            mx = fmaxf(mx, __shfl_xor(mx, 16));
            mx = fmaxf(mx, __shfl_xor(mx, 32));
            float sum = 0.f;
#pragma unroll
            for (int mt = 0; mt < 4; mt++)
#pragma unroll
                for (int r = 0; r < 4; r++) {
                    float e = __expf(s[mt][nt][r] - mx);
                    s[mt][nt][r] = e;
                    sum += e;
                }
            sum += __shfl_xor(sum, 16);
            sum += __shfl_xor(sum, 32);
            float inv = 1.f / sum;
#pragma unroll
            for (int mt = 0; mt < 4; mt++) {
                unsigned int p01 = (unsigned int)f2bf(s[mt][nt][0] * inv) | ((unsigned int)f2bf(s[mt][nt][1] * inv) << 16);
                unsigned int p23 = (unsigned int)f2bf(s[mt][nt][2] * inv) | ((unsigned int)f2bf(s[mt][nt][3] * inv) << 16);
                uint2 pk; pk.x = p01; pk.y = p23;
                *(uint2*)&P[(unsigned)q * 72 + mt * 16 + g * 4] = pk;
            }
        }

        // O = P * V via MFMA
        bf16x8 vf[2][2];
#pragma unroll
        for (int ks = 0; ks < 2; ks++)
#pragma unroll
            for (int dt = 0; dt < 2; dt++)
                vf[ks][dt] = *(const bf16x8*)&Vt[(dt * 16 + l15) * 72 + ks * 32 + g * 8];

        f32x4 o[4][2] = {};
#pragma unroll
        for (int nt = 0; nt < 4; nt++) {
            bf16x8 pf0 = *(const bf16x8*)&P[(nt * 16 + l15) * 72 + g * 8];
            bf16x8 pf1 = *(const bf16x8*)&P[(nt * 16 + l15) * 72 + 32 + g * 8];
#pragma unroll
            for (int dt = 0; dt < 2; dt++) {
                o[nt][dt] = __builtin_amdgcn_mfma_f32_16x16x32_bf16(pf0, vf[0][dt], o[nt][dt], 0, 0, 0);
                o[nt][dt] = __builtin_amdgcn_mfma_f32_16x16x32_bf16(pf1, vf[1][dt], o[nt][dt], 0, 0, 0);
            }
        }

        // write O to LDS tile 'head' in sA layout: row q, k-slot XOR'd with (q&3)^((q>>2)&3)=r^g
        {
            const int sw = /* per (nt,r): q&3 = r, (q>>2)&3 = g */ 0; (void)sw;
            u16* tile = &outT[head * 2048];
#pragma unroll
            for (int nt = 0; nt < 4; nt++)
#pragma unroll
                for (int r = 0; r < 4; r++) {
                    int q = nt * 16 + 4 * g + r;
                    int sx = r ^ g;
                    int s0 = (l15 >> 3) ^ sx;
                    int s1 = (2 + (l15 >> 3)) ^ sx;
                    tile[q * 32 + s0 * 8 + (l15 & 7)] = f2bf(o[nt][0][r]);
                    tile[q * 32 + s1 * 8 + (l15 & 7)] = f2bf(o[nt][1][r]);
                }
        }
    }

    if (tid < 64) { stats[tid][0] = 0.f; stats[tid][1] = 0.f; }
    __syncthreads();   // all O tiles ready, stats zeroed

    // ================= proj phase: wave w -> cols [w*96, w*96+96) ===========
    f32x4 acc[4][6] = {};
    const int ssr = (g ^ (l15 & 3) ^ ((l15 >> 2) & 3)) * 8;
    const int colw = wave * 96;
#pragma unroll
    for (int kt = 0; kt < 12; kt++) {
        bf16x8 af[4];
#pragma unroll
        for (int m = 0; m < 4; m++)
            af[m] = *(const bf16x8*)&outT[kt * 2048 + (m * 16 + l15) * 32 + ssr];
        bf16x8 bfr[6];
#pragma unroll
        for (int n = 0; n < 6; n++)
            bfr[n] = *(const bf16x8*)&projw[(size_t)(colw + n * 16 + l15) * 384 + kt * 32 + g * 8];
#pragma unroll
        for (int m = 0; m < 4; m++)
#pragma unroll
            for (int n = 0; n < 6; n++)
                acc[m][n] = __builtin_amdgcn_mfma_f32_16x16x32_bf16(af[m], bfr[n], acc[m][n], 0, 0, 0);
    }

    // bias + resid -> y1 (scattered), accumulate LN2 stats
    float pb[6];
#pragma unroll
    for (int n = 0; n < 6; n++) pb[n] = projb[colw + n * 16 + l15];

    const int b_ = win >> 6;
#pragma unroll
    for (int m = 0; m < 4; m++) {
#pragma unroll
        for (int r = 0; r < 4; r++) {
            int q = m * 16 + 4 * g + r;
            bool valid = q < NN;
            size_t obase = 0;
            if (valid) {
                int hr = (wi >> 3) * 7 + q / 7;
                int wcl = (wi & 7) * 7 + q % 7;
                int hf = hr + 3; if (hf >= HH) hf -= HH;
                int wf = wcl + 3; if (wf >= WW) wf -= WW;
                obase = ((size_t)b_ * 3136 + hf * WW + wf) * DIM;
            }
            float s1 = 0.f, s2 = 0.f;
#pragma unroll
            for (int n = 0; n < 6; n++) {
                float v = acc[m][n][r] + pb[n];
                if (valid) {
                    int col = colw + n * 16 + l15;
                    v += x[obase + col];
                    y1[obase + col] = v;
                }
                acc[m][n][r] = v;
                s1 += v; s2 += v * v;
            }
#pragma unroll
            for (int off = 1; off < 16; off <<= 1) {
                s1 += __shfl_xor(s1, off);
                s2 += __shfl_xor(s2, off);
            }
            if (l15 == 0) {
                atomicAdd(&stats[q][0], s1);
                atomicAdd(&stats[q][1], s2);
            }
        }
    }
    __syncthreads();

    // LN2 write (bf16, scattered token order)
    float w6[6], b6[6];
#pragma unroll
    for (int n = 0; n < 6; n++) {
        w6[n] = n2w[colw + n * 16 + l15];
        b6[n] = n2b[colw + n * 16 + l15];
    }
#pragma unroll
    for (int m = 0; m < 4; m++) {
#pragma unroll
        for (int r = 0; r < 4; r++) {
            int q = m * 16 + 4 * g + r;
            if (q >= NN) continue;
            int hr = (wi >> 3) * 7 + q / 7;
            int wcl = (wi & 7) * 7 + q % 7;
            int hf = hr + 3; if (hf >= HH) hf -= HH;
            int wf = wcl + 3; if (wf >= WW) wf -= WW;
            size_t obase = ((size_t)b_ * 3136 + hf * WW + wf) * DIM;
            float mu = stats[q][0] * (1.f / DIM);
            float rstd = rsqrtf(stats[q][1] * (1.f / DIM) - mu * mu + 1e-5f);
#pragma unroll
            for (int n = 0; n < 6; n++) {
                int col = colw + n * 16 + l15;
                float v = (acc[m][n][r] - mu) * rstd * w6[n] + b6[n];
                ln2out[obase + col] = f2bf(v);
            }
        }
    }
}

// ---------------- launch ------------------------------------------------------
extern "C" void kernel_launch(void* const* d_in, const int* in_sizes, int n_in,
                              void* d_out, int out_size, void* d_ws, size_t ws_size,
                              hipStream_t stream)
{
    const float* x      = (const float*)d_in[0];
    const float* qkv_w  = (const float*)d_in[1];
    const float* qkv_b  = (const float*)d_in[2];
    const float* proj_w = (const float*)d_in[3];
    const float* proj_b = (const float*)d_in[4];
    const float* rel_b  = (const float*)d_in[5];
    const float* n1w    = (const float*)d_in[6];
    const float* n1b    = (const float*)d_in[7];
    const float* n2w    = (const float*)d_in[8];
    const float* n2b    = (const float*)d_in[9];
    const float* w1     = (const float*)d_in[10];
    const float* b1     = (const float*)d_in[11];
    const float* w2     = (const float*)d_in[12];
    const float* b2     = (const float*)d_in[13];

    char* ws = (char*)d_ws;
    u16* hidden  = (u16*)(ws);                       // 100352x1536 bf16 (MLP hidden)
    u16* qkvbuf  = hidden;                           // 100352x1152 bf16 (aliases hidden)
    float* Tb    = (float*)(ws + 231211008);         // 4x12x64x64 f32 bias table
    u16* wxbuf   = (u16*)(ws + 308281344);           // 100352x384 bf16 (wx / ln2)
    u16* qkv_wt  = (u16*)(ws + 385351680);           // 1152x384
    u16* proj_wt = (u16*)(ws + 386236416);           // 384x384
    u16* w1t     = (u16*)(ws + 386531328);           // 1536x384
    u16* w2t     = (u16*)(ws + 387710976);           // 384x1536

    castT<<<(1152*384 + 255) / 256, 256, 0, stream>>>(qkv_w, qkv_wt, 384, 1152);
    castT<<<(384*384  + 255) / 256, 256, 0, stream>>>(proj_w, proj_wt, 384, 384);
    castT<<<(384*1536 + 255) / 256, 256, 0, stream>>>(w1, w1t, 384, 1536);
    castT<<<(1536*384 + 255) / 256, 256, 0, stream>>>(w2, w2t, 1536, 384);
    bias_kernel<<<48, 256, 0, stream>>>(rel_b, Tb);

    // LN1 + roll + window partition
    ln_kernel<<<NTOK / 4, 256, 0, stream>>>(x, n1w, n1b, wxbuf);
    // QKV GEMM
    gemm_kernel<0><<<784 * 9, 256, 0, stream>>>(wxbuf, qkv_wt, qkv_b, nullptr, qkvbuf, 1152, 384, 9);
    // fused attention + proj + residual + LN2
    attn_proj_kernel<<<NWIN, 256, 0, stream>>>(qkvbuf, Tb, proj_wt, proj_b, x,
                                               n2w, n2b, (float*)d_out, wxbuf);
    // MLP1 + GELU -> hidden
    gemm_kernel<2><<<784 * 12, 256, 0, stream>>>(wxbuf, w1t, b1, nullptr, hidden, 1536, 384, 12);
    // MLP2 + residual(y1) -> d_out (f32)
    gemm_kernel<3><<<784 * 3, 256, 0, stream>>>(hidden, w2t, b2, (const float*)d_out, d_out, 384, 1536, 3);
}

// Round 11
// 907.334 us; speedup vs baseline: 1.3653x; 1.0926x over previous
//
#include <hip/hip_runtime.h>
#include <hip/hip_bf16.h>

typedef unsigned short u16;
typedef __bf16 bf16x8 __attribute__((ext_vector_type(8)));
typedef float f32x4 __attribute__((ext_vector_type(4)));

#define HH 56
#define WW 56
#define DIM 384
#define NTOK 100352   // 32*3136
#define NWIN 2048     // 32*64
#define NN 49

__device__ __forceinline__ u16 f2bf(float f) {
    __hip_bfloat16 h = __float2bfloat16(f);
    return *reinterpret_cast<u16*>(&h);
}
__device__ __forceinline__ float bf2f(u16 u) {
    union { unsigned int i; float f; } c; c.i = ((unsigned int)u) << 16; return c.f;
}

// exact-GELU: gelu(x) = 0.5*x*(1+erf(x/sqrt2)), erf via A&S 7.1.26 (max err 1.5e-7)
__device__ __forceinline__ float fast_gelu(float x) {
    float au = fabsf(x) * 0.70710678118654752f;
    float t = __builtin_amdgcn_rcpf(fmaf(0.3275911f, au, 1.0f));
    float p = fmaf(t, 1.061405429f, -1.453152027f);
    p = fmaf(t, p, 1.421413741f);
    p = fmaf(t, p, -0.284496736f);
    p = fmaf(t, p, 0.254829592f);
    p = p * t;
    float e = __expf(-au * au);
    float erfau = fmaf(-p, e, 1.0f);
    float erfx = __builtin_copysignf(erfau, x);
    return 0.5f * x * (1.0f + erfx);
}

#define GLD_LDS(gp, lp) __builtin_amdgcn_global_load_lds( \
    (const __attribute__((address_space(1))) void*)(gp), \
    (__attribute__((address_space(3))) void*)(lp), 16, 0, 0)

// ---------------- weight transpose + cast: in (K,N) f32 -> out (N,K) bf16 ----
__global__ void castT(const float* __restrict__ in, u16* __restrict__ out, int K, int N) {
    int i = blockIdx.x * 256 + threadIdx.x;
    if (i < N * K) {
        int n = i / K, kk = i - n * K;
        out[i] = f2bf(in[(size_t)kk * N + n]);
    }
}

// ---------------- bias table: Tb[ty][head][q][kk] = rel_bias + mask (+pad) ---
__global__ void bias_kernel(const float* __restrict__ rel_bias, float* __restrict__ Tb) {
    int ty = blockIdx.x / 12, h = blockIdx.x - ty * 12;
    for (int i = threadIdx.x; i < 4096; i += 256) {
        int q = i >> 6, kk = i & 63;
        float v;
        if (kk >= 49) v = -1e30f;
        else if (q >= 49) v = 0.f;
        else {
            int rn = q / 7, cn = q - rn * 7;
            int rm = kk / 7, cm = kk - rm * 7;
            float rb = rel_bias[((rn - rm + 6) * 13 + (cn - cm + 6)) * 12 + h];
            int h0 = (ty >> 1) ? 49 : 0;
            int w0 = (ty & 1) ? 49 : 0;
            int hn = h0 + rn, hm = h0 + rm, wn = w0 + cn, wm = w0 + cm;
            int regn = (hn < 49 ? 0 : (hn < 53 ? 1 : 2)) * 3 + (wn < 49 ? 0 : (wn < 53 ? 1 : 2));
            int regm = (hm < 49 ? 0 : (hm < 53 ? 1 : 2)) * 3 + (wm < 49 ? 0 : (wm < 53 ? 1 : 2));
            v = rb + ((regn == regm) ? 0.f : -10000.f);
        }
        Tb[(size_t)blockIdx.x * 4096 + i] = v;
    }
}

// ---------------- LayerNorm (one wave per token). WIN_MAP: write to windowed pos
template<bool WIN_MAP>
__global__ __launch_bounds__(256) void ln_kernel(
    const float* __restrict__ x, const float* __restrict__ w, const float* __restrict__ b,
    u16* __restrict__ out)
{
    int token = blockIdx.x * 4 + (threadIdx.x >> 6);
    int lane = threadIdx.x & 63;
    const float* row = x + (size_t)token * DIM;
    float v[6]; float sum = 0.f, sq = 0.f;
#pragma unroll
    for (int j = 0; j < 3; j++) {
        float2 p = *(const float2*)(row + lane * 2 + j * 128);
        v[2*j] = p.x; v[2*j+1] = p.y;
        sum += p.x + p.y; sq += p.x * p.x + p.y * p.y;
    }
#pragma unroll
    for (int off = 32; off; off >>= 1) { sum += __shfl_xor(sum, off); sq += __shfl_xor(sq, off); }
    float mu = sum * (1.f / DIM);
    float rstd = rsqrtf(sq * (1.f / DIM) - mu * mu + 1e-5f);
    size_t obase;
    if (WIN_MAP) {
        int b_ = token / 3136, hw = token - b_ * 3136;
        int h = hw / WW, wc_ = hw - h * WW;
        int hr = h - 3; if (hr < 0) hr += HH;
        int wr = wc_ - 3; if (wr < 0) wr += WW;
        int win = b_ * 64 + (hr / 7) * 8 + (wr / 7);
        int n = (hr % 7) * 7 + (wr % 7);
        obase = ((size_t)win * NN + n) * DIM;
    } else {
        obase = (size_t)token * DIM;
    }
#pragma unroll
    for (int j = 0; j < 3; j++) {
        int c = lane * 2 + j * 128;
        float a0 = (v[2*j]   - mu) * rstd * w[c]   + b[c];
        float a1 = (v[2*j+1] - mu) * rstd * w[c+1] + b[c+1];
        unsigned int pair = (unsigned int)f2bf(a0) | ((unsigned int)f2bf(a1) << 16);
        *(unsigned int*)(out + obase + c) = pair;
    }
}

// ---------------- GEMM: C = A(MxK) * Bt(NxK)^T + bias, bf16 in, fp32 acc -----
// 256x128 tile, 8 waves (512 thr), 3-buffer counted gld_lds pipeline (72 KB
// LDS -> 2 blocks/CU = 16 waves/CU), slot-XOR swizzle, XCD-bijective swizzle.
template<int EPI>
__global__ __launch_bounds__(512, 4) void gemm_kernel(
    const u16* __restrict__ A, const u16* __restrict__ Bt,
    const float* __restrict__ bias, const float* __restrict__ resid,
    void* __restrict__ outp, int N, int K, int BNT)
{
    __shared__ u16 sA[3][8192];   // 256 x 32
    __shared__ u16 sB[3][4096];   // 128 x 32
    const int tid = threadIdx.x;
    const int lane = tid & 63;
    const int wave = tid >> 6;
    const int wr = wave >> 1, wc = wave & 1;   // 4 x 2 wave grid

    const int q8 = gridDim.x >> 3;
    const int wg = (blockIdx.x & 7) * q8 + (blockIdx.x >> 3);
    const int bm = wg / BNT, bn = wg - bm * BNT;

    f32x4 acc[4][4] = {};

    // staging: thread -> row r0 = tid>>2 (0..127), LDS slot tid&3.
    // global k-group pre-swizzled: lds[row][slot] holds kg = slot^(row&3)^((row>>2)&3)
    const int r0 = tid >> 2;
    const int sg = (tid & 3) ^ (r0 & 3) ^ ((r0 >> 2) & 3);
    const u16* Arow0 = A + (size_t)(bm * 256 + r0) * K + sg * 8;
    const u16* Arow1 = Arow0 + (size_t)128 * K;       // rows 128..255 (same XOR class)
    const u16* Brow0 = Bt + (size_t)(bn * 128 + r0) * K + sg * 8;

    const int nt = K >> 5;

#define STAGE(t, buf) do { \
        int kt_ = (t) * 32; \
        GLD_LDS(Arow0 + kt_, &sA[buf][wave * 512]); \
        GLD_LDS(Arow1 + kt_, &sA[buf][4096 + wave * 512]); \
        GLD_LDS(Brow0 + kt_, &sB[buf][wave * 512]); \
    } while (0)

    STAGE(0, 0); STAGE(1, 1);

    const int l15 = lane & 15, g = lane >> 4;
    const int ssr = (g ^ (l15 & 3) ^ ((l15 >> 2) & 3)) * 8;  // de-swizzled k-slot

    int buf = 0;
    for (int t = 0; t < nt; t++) {
        if (t + 1 < nt) asm volatile("s_waitcnt vmcnt(3)" ::: "memory");  // own tile landed
        else            asm volatile("s_waitcnt vmcnt(0)" ::: "memory");
        __builtin_amdgcn_s_barrier();
        __builtin_amdgcn_sched_barrier(0);
        if (t + 2 < nt) {
            int nb = buf + 2; if (nb >= 3) nb -= 3;
            STAGE(t + 2, nb);
        }
        bf16x8 af[4], bfr[4];
#pragma unroll
        for (int m = 0; m < 4; m++) {
            int row = wr * 64 + m * 16 + l15;
            af[m] = *(const bf16x8*)&sA[buf][row * 32 + ssr];
        }
#pragma unroll
        for (int n = 0; n < 4; n++) {
            int row = wc * 64 + n * 16 + l15;
            bfr[n] = *(const bf16x8*)&sB[buf][row * 32 + ssr];
        }
#pragma unroll
        for (int m = 0; m < 4; m++)
#pragma unroll
            for (int n = 0; n < 4; n++)
                acc[m][n] = __builtin_amdgcn_mfma_f32_16x16x32_bf16(af[m], bfr[n], acc[m][n], 0, 0, 0);
        buf = buf + 1; if (buf >= 3) buf = 0;
    }
#undef STAGE

    // ---- epilogue ----
    const int col0 = bn * 128 + wc * 64 + l15;
    float bias4[4];
#pragma unroll
    for (int nn = 0; nn < 4; nn++) bias4[nn] = bias[col0 + nn * 16];

#pragma unroll
    for (int m = 0; m < 4; m++) {
#pragma unroll
        for (int r = 0; r < 4; r++) {
            int row = bm * 256 + wr * 64 + m * 16 + (g << 2) + r;
            size_t obase;
            if (EPI == 1) {
                int win = row / NN, n = row - win * NN;
                int b_ = win >> 6, wi = win & 63;
                int hr = (wi >> 3) * 7 + n / 7;
                int wcl = (wi & 7) * 7 + n % 7;
                int hf = hr + 3; if (hf >= HH) hf -= HH;
                int wf = wcl + 3; if (wf >= WW) wf -= WW;
                obase = ((size_t)b_ * 3136 + hf * WW + wf) * DIM;
            } else {
                obase = (size_t)row * N;
            }
#pragma unroll
            for (int nn = 0; nn < 4; nn++) {
                int col = col0 + nn * 16;
                float val = acc[m][nn][r] + bias4[nn];
                if (EPI == 0) {
                    ((u16*)outp)[obase + col] = f2bf(val);
                } else if (EPI == 1) {
                    ((float*)outp)[obase + col] = val + resid[obase + col];
                } else if (EPI == 2) {
                    ((u16*)outp)[obase + col] = f2bf(fast_gelu(val));
                } else {
                    ((float*)outp)[obase + col] = val + resid[obase + col];
                }
            }
        }
    }
}

// ---------------- MFMA windowed attention: one wave per (window, head) -------
__global__ __launch_bounds__(256) void attn_kernel(
    const u16* __restrict__ qkv, const float* __restrict__ Tb,
    u16* __restrict__ attn_out)
{
    // per-wave LDS: Vt[32][72] + P[64][72] (u16), 13824 B/wave
    __shared__ u16 smem[4][6912];
    const int win = blockIdx.x;
    const int wave = threadIdx.x >> 6;
    const int lane = threadIdx.x & 63;
    const int head = blockIdx.y * 4 + wave;
    const int l15 = lane & 15, g = lane >> 4;

    u16* Vt = smem[wave];
    u16* P  = Vt + 2304;

    const u16* qkvw = qkv + (size_t)win * NN * 1152 + head * 32;

    // ---- stage V transposed (zero-pad rows >= 49) ----
    {
        int m = lane;
        bool real = m < NN;
        const u16* vrow = qkvw + (size_t)(real ? m : 0) * 1152 + 768;
        int4 z = {0,0,0,0};
        int4 c0 = real ? *(const int4*)(vrow)      : z;
        int4 c1 = real ? *(const int4*)(vrow + 8)  : z;
        int4 c2 = real ? *(const int4*)(vrow + 16) : z;
        int4 c3 = real ? *(const int4*)(vrow + 24) : z;
        u16 vals[32];
        *(int4*)&vals[0]  = c0; *(int4*)&vals[8]  = c1;
        *(int4*)&vals[16] = c2; *(int4*)&vals[24] = c3;
#pragma unroll
        for (int d = 0; d < 32; d++) Vt[d * 72 + m] = vals[d];
    }

    // ---- S^T = K * Q^T via MFMA (rows clamped to 48: no garbage) ----
    bf16x8 kf[4], qf[4];
#pragma unroll
    for (int t = 0; t < 4; t++) {
        int row = t * 16 + l15; if (row > 48) row = 48;
        const u16* base = qkvw + (size_t)row * 1152 + g * 8;
        kf[t] = *(const bf16x8*)(base + 384);
        qf[t] = *(const bf16x8*)(base);
    }
    f32x4 s[4][4];   // [key-tile mt][query-tile nt]
#pragma unroll
    for (int mt = 0; mt < 4; mt++)
#pragma unroll
        for (int nt = 0; nt < 4; nt++) {
            f32x4 zero = {};
            s[mt][nt] = __builtin_amdgcn_mfma_f32_16x16x32_bf16(kf[mt], qf[nt], zero, 0, 0, 0);
        }

    // ---- bias + mask + softmax (query = nt*16 + l15, keys in regs) ----
    const int wi = win & 63;
    const int ty = (((wi >> 3) == 7) ? 2 : 0) + (((wi & 7) == 7) ? 1 : 0);
    const float* tbb = Tb + (((size_t)ty * 12 + head) << 12);
    const float SCALE = 0.17677669529663687f;
#pragma unroll
    for (int nt = 0; nt < 4; nt++) {
        int q = nt * 16 + l15;
        const float* trow = tbb + q * 64 + g * 4;
        f32x4 b[4];
#pragma unroll
        for (int mt = 0; mt < 4; mt++) b[mt] = *(const f32x4*)(trow + mt * 16);
        float mx = -3e38f;
#pragma unroll
        for (int mt = 0; mt < 4; mt++)
#pragma unroll
            for (int r = 0; r < 4; r++) {
                float v = s[mt][nt][r] * SCALE + b[mt][r];
                s[mt][nt][r] = v;
                mx = fmaxf(mx, v);
            }
        mx = fmaxf(mx, __shfl_xor(mx, 16));
        mx = fmaxf(mx, __shfl_xor(mx, 32));
        float sum = 0.f;
#pragma unroll
        for (int mt = 0; mt < 4; mt++)
#pragma unroll
            for (int r = 0; r < 4; r++) {
                float e = __expf(s[mt][nt][r] - mx);
                s[mt][nt][r] = e;
                sum += e;
            }
        sum += __shfl_xor(sum, 16);
        sum += __shfl_xor(sum, 32);
        float inv = 1.f / sum;
#pragma unroll
        for (int mt = 0; mt < 4; mt++) {
            unsigned int p01 = (unsigned int)f2bf(s[mt][nt][0] * inv) | ((unsigned int)f2bf(s[mt][nt][1] * inv) << 16);
            unsigned int p23 = (unsigned int)f2bf(s[mt][nt][2] * inv) | ((unsigned int)f2bf(s[mt][nt][3] * inv) << 16);
            uint2 pk; pk.x = p01; pk.y = p23;
            *(uint2*)&P[(unsigned)q * 72 + mt * 16 + g * 4] = pk;
        }
    }

    // ---- O = P * V via MFMA ----
    bf16x8 vf[2][2];
#pragma unroll
    for (int ks = 0; ks < 2; ks++)
#pragma unroll
        for (int dt = 0; dt < 2; dt++)
            vf[ks][dt] = *(const bf16x8*)&Vt[(dt * 16 + l15) * 72 + ks * 32 + g * 8];

    f32x4 o[4][2] = {};
#pragma unroll
    for (int nt = 0; nt < 4; nt++) {
        bf16x8 pf0 = *(const bf16x8*)&P[(nt * 16 + l15) * 72 + g * 8];
        bf16x8 pf1 = *(const bf16x8*)&P[(nt * 16 + l15) * 72 + 32 + g * 8];
#pragma unroll
        for (int dt = 0; dt < 2; dt++) {
            o[nt][dt] = __builtin_amdgcn_mfma_f32_16x16x32_bf16(pf0, vf[0][dt], o[nt][dt], 0, 0, 0);
            o[nt][dt] = __builtin_amdgcn_mfma_f32_16x16x32_bf16(pf1, vf[1][dt], o[nt][dt], 0, 0, 0);
        }
    }

    // ---- write out ----
#pragma unroll
    for (int nt = 0; nt < 4; nt++)
#pragma unroll
        for (int r = 0; r < 4; r++) {
            int q = nt * 16 + 4 * g + r;
            if (q < NN) {
                size_t ob = ((size_t)win * NN + q) * DIM + head * 32;
                attn_out[ob + l15]      = f2bf(o[nt][0][r]);
                attn_out[ob + 16 + l15] = f2bf(o[nt][1][r]);
            }
        }
}

// ---------------- launch ------------------------------------------------------
extern "C" void kernel_launch(void* const* d_in, const int* in_sizes, int n_in,
                              void* d_out, int out_size, void* d_ws, size_t ws_size,
                              hipStream_t stream)
{
    const float* x      = (const float*)d_in[0];
    const float* qkv_w  = (const float*)d_in[1];
    const float* qkv_b  = (const float*)d_in[2];
    const float* proj_w = (const float*)d_in[3];
    const float* proj_b = (const float*)d_in[4];
    const float* rel_b  = (const float*)d_in[5];
    const float* n1w    = (const float*)d_in[6];
    const float* n1b    = (const float*)d_in[7];
    const float* n2w    = (const float*)d_in[8];
    const float* n2b    = (const float*)d_in[9];
    const float* w1     = (const float*)d_in[10];
    const float* b1     = (const float*)d_in[11];
    const float* w2     = (const float*)d_in[12];
    const float* b2     = (const float*)d_in[13];

    char* ws = (char*)d_ws;
    u16* hidden  = (u16*)(ws);                       // 100352x1536 bf16 (MLP hidden)
    u16* qkvbuf  = hidden;                           // 100352x1152 bf16 (aliases hidden)
    float* Tb    = (float*)(ws + 231211008);         // 4x12x64x64 f32 bias table
    u16* wxbuf   = (u16*)(ws + 308281344);           // 100352x384 bf16 (wx / attn_out / ln2)
    u16* qkv_wt  = (u16*)(ws + 385351680);           // 1152x384
    u16* proj_wt = (u16*)(ws + 386236416);           // 384x384
    u16* w1t     = (u16*)(ws + 386531328);           // 1536x384
    u16* w2t     = (u16*)(ws + 387710976);           // 384x1536

    castT<<<(1152*384 + 255) / 256, 256, 0, stream>>>(qkv_w, qkv_wt, 384, 1152);
    castT<<<(384*384  + 255) / 256, 256, 0, stream>>>(proj_w, proj_wt, 384, 384);
    castT<<<(384*1536 + 255) / 256, 256, 0, stream>>>(w1, w1t, 384, 1536);
    castT<<<(1536*384 + 255) / 256, 256, 0, stream>>>(w2, w2t, 1536, 384);
    bias_kernel<<<48, 256, 0, stream>>>(rel_b, Tb);

    // LN1 + roll + window partition
    ln_kernel<true><<<NTOK / 4, 256, 0, stream>>>(x, n1w, n1b, wxbuf);
    // QKV GEMM (256x128 tiles: 392 x 9 blocks)
    gemm_kernel<0><<<392 * 9, 512, 0, stream>>>(wxbuf, qkv_wt, qkv_b, nullptr, qkvbuf, 1152, 384, 9);
    // attention (overwrites wxbuf with attn output, windowed layout)
    attn_kernel<<<dim3(NWIN, 3), 256, 0, stream>>>(qkvbuf, Tb, wxbuf);
    // proj GEMM + window reverse + roll + residual -> y1 in d_out (f32)
    gemm_kernel<1><<<392 * 3, 512, 0, stream>>>(wxbuf, proj_wt, proj_b, x, d_out, 384, 384, 3);
    // LN2 on y1 -> wxbuf (bf16)
    ln_kernel<false><<<NTOK / 4, 256, 0, stream>>>((const float*)d_out, n2w, n2b, wxbuf);
    // MLP1 + GELU -> hidden
    gemm_kernel<2><<<392 * 12, 512, 0, stream>>>(wxbuf, w1t, b1, nullptr, hidden, 1536, 384, 12);
    // MLP2 + residual(y1) -> d_out (f32)
    gemm_kernel<3><<<392 * 3, 512, 0, stream>>>(hidden, w2t, b2, (const float*)d_out, d_out, 384, 1536, 3);
}

// Round 12
// 895.576 us; speedup vs baseline: 1.3833x; 1.0131x over previous
//
#include <hip/hip_runtime.h>
#include <hip/hip_bf16.h>

typedef unsigned short u16;
typedef __bf16 bf16x8 __attribute__((ext_vector_type(8)));
typedef float f32x4 __attribute__((ext_vector_type(4)));

#define HH 56
#define WW 56
#define DIM 384
#define NTOK 100352   // 32*3136
#define NWIN 2048     // 32*64
#define NN 49

__device__ __forceinline__ u16 f2bf(float f) {
    __hip_bfloat16 h = __float2bfloat16(f);
    return *reinterpret_cast<u16*>(&h);
}
__device__ __forceinline__ float bf2f(u16 u) {
    union { unsigned int i; float f; } c; c.i = ((unsigned int)u) << 16; return c.f;
}

// exact-GELU: gelu(x) = 0.5*x*(1+erf(x/sqrt2)), erf via A&S 7.1.26 (max err 1.5e-7)
__device__ __forceinline__ float fast_gelu(float x) {
    float au = fabsf(x) * 0.70710678118654752f;
    float t = __builtin_amdgcn_rcpf(fmaf(0.3275911f, au, 1.0f));
    float p = fmaf(t, 1.061405429f, -1.453152027f);
    p = fmaf(t, p, 1.421413741f);
    p = fmaf(t, p, -0.284496736f);
    p = fmaf(t, p, 0.254829592f);
    p = p * t;
    float e = __expf(-au * au);
    float erfau = fmaf(-p, e, 1.0f);
    float erfx = __builtin_copysignf(erfau, x);
    return 0.5f * x * (1.0f + erfx);
}

#define GLD_LDS(gp, lp) __builtin_amdgcn_global_load_lds( \
    (const __attribute__((address_space(1))) void*)(gp), \
    (__attribute__((address_space(3))) void*)(lp), 16, 0, 0)

// ---------------- weight transpose + cast: in (K,N) f32 -> out (N,K) bf16 ----
__global__ void castT(const float* __restrict__ in, u16* __restrict__ out, int K, int N) {
    int i = blockIdx.x * 256 + threadIdx.x;
    if (i < N * K) {
        int n = i / K, kk = i - n * K;
        out[i] = f2bf(in[(size_t)kk * N + n]);
    }
}

// ---------------- bias table: Tb[ty][head][q][kk] = rel_bias + mask (+pad) ---
__global__ void bias_kernel(const float* __restrict__ rel_bias, float* __restrict__ Tb) {
    int ty = blockIdx.x / 12, h = blockIdx.x - ty * 12;
    for (int i = threadIdx.x; i < 4096; i += 256) {
        int q = i >> 6, kk = i & 63;
        float v;
        if (kk >= 49) v = -1e30f;
        else if (q >= 49) v = 0.f;
        else {
            int rn = q / 7, cn = q - rn * 7;
            int rm = kk / 7, cm = kk - rm * 7;
            float rb = rel_bias[((rn - rm + 6) * 13 + (cn - cm + 6)) * 12 + h];
            int h0 = (ty >> 1) ? 49 : 0;
            int w0 = (ty & 1) ? 49 : 0;
            int hn = h0 + rn, hm = h0 + rm, wn = w0 + cn, wm = w0 + cm;
            int regn = (hn < 49 ? 0 : (hn < 53 ? 1 : 2)) * 3 + (wn < 49 ? 0 : (wn < 53 ? 1 : 2));
            int regm = (hm < 49 ? 0 : (hm < 53 ? 1 : 2)) * 3 + (wm < 49 ? 0 : (wm < 53 ? 1 : 2));
            v = rb + ((regn == regm) ? 0.f : -10000.f);
        }
        Tb[(size_t)blockIdx.x * 4096 + i] = v;
    }
}

// ---------------- LayerNorm (one wave per token). WIN_MAP: write to windowed pos
template<bool WIN_MAP>
__global__ __launch_bounds__(256) void ln_kernel(
    const float* __restrict__ x, const float* __restrict__ w, const float* __restrict__ b,
    u16* __restrict__ out)
{
    int token = blockIdx.x * 4 + (threadIdx.x >> 6);
    int lane = threadIdx.x & 63;
    const float* row = x + (size_t)token * DIM;
    float v[6]; float sum = 0.f, sq = 0.f;
#pragma unroll
    for (int j = 0; j < 3; j++) {
        float2 p = *(const float2*)(row + lane * 2 + j * 128);
        v[2*j] = p.x; v[2*j+1] = p.y;
        sum += p.x + p.y; sq += p.x * p.x + p.y * p.y;
    }
#pragma unroll
    for (int off = 32; off; off >>= 1) { sum += __shfl_xor(sum, off); sq += __shfl_xor(sq, off); }
    float mu = sum * (1.f / DIM);
    float rstd = rsqrtf(sq * (1.f / DIM) - mu * mu + 1e-5f);
    size_t obase;
    if (WIN_MAP) {
        int b_ = token / 3136, hw = token - b_ * 3136;
        int h = hw / WW, wc_ = hw - h * WW;
        int hr = h - 3; if (hr < 0) hr += HH;
        int wr = wc_ - 3; if (wr < 0) wr += WW;
        int win = b_ * 64 + (hr / 7) * 8 + (wr / 7);
        int n = (hr % 7) * 7 + (wr % 7);
        obase = ((size_t)win * NN + n) * DIM;
    } else {
        obase = (size_t)token * DIM;
    }
#pragma unroll
    for (int j = 0; j < 3; j++) {
        int c = lane * 2 + j * 128;
        float a0 = (v[2*j]   - mu) * rstd * w[c]   + b[c];
        float a1 = (v[2*j+1] - mu) * rstd * w[c+1] + b[c+1];
        unsigned int pair = (unsigned int)f2bf(a0) | ((unsigned int)f2bf(a1) << 16);
        *(unsigned int*)(out + obase + c) = pair;
    }
}

// ---------------- GEMM: C = A(MxK) * Bt(NxK)^T + bias, bf16 in, fp32 acc -----
// 256x128 tile, 8 waves, 3-buffer counted gld_lds pipeline, slot-XOR swizzle,
// XCD-bijective swizzle. REV: walk bm descending (per-XCD LIFO) so the next
// kernel in the chain reads this kernel's output newest-first out of L3.
template<int EPI, bool REV>
__global__ __launch_bounds__(512, 4) void gemm_kernel(
    const u16* __restrict__ A, const u16* __restrict__ Bt,
    const float* __restrict__ bias, const float* __restrict__ resid,
    void* __restrict__ outp, int N, int K, int BNT)
{
    __shared__ u16 sA[3][8192];   // 256 x 32
    __shared__ u16 sB[3][4096];   // 128 x 32
    const int tid = threadIdx.x;
    const int lane = tid & 63;
    const int wave = tid >> 6;
    const int wr = wave >> 1, wc = wave & 1;   // 4 x 2 wave grid

    const int q8 = gridDim.x >> 3;
    int wg = (blockIdx.x & 7) * q8 + (blockIdx.x >> 3);
    if (REV) wg = gridDim.x - 1 - wg;          // per-chunk descending bm
    const int bm = wg / BNT, bn = wg - bm * BNT;

    f32x4 acc[4][4] = {};

    const int r0 = tid >> 2;
    const int sg = (tid & 3) ^ (r0 & 3) ^ ((r0 >> 2) & 3);
    const u16* Arow0 = A + (size_t)(bm * 256 + r0) * K + sg * 8;
    const u16* Arow1 = Arow0 + (size_t)128 * K;
    const u16* Brow0 = Bt + (size_t)(bn * 128 + r0) * K + sg * 8;

    const int nt = K >> 5;

#define STAGE(t, buf) do { \
        int kt_ = (t) * 32; \
        GLD_LDS(Arow0 + kt_, &sA[buf][wave * 512]); \
        GLD_LDS(Arow1 + kt_, &sA[buf][4096 + wave * 512]); \
        GLD_LDS(Brow0 + kt_, &sB[buf][wave * 512]); \
    } while (0)

    STAGE(0, 0); STAGE(1, 1);

    const int l15 = lane & 15, g = lane >> 4;
    const int ssr = (g ^ (l15 & 3) ^ ((l15 >> 2) & 3)) * 8;

    int buf = 0;
    for (int t = 0; t < nt; t++) {
        if (t + 1 < nt) asm volatile("s_waitcnt vmcnt(3)" ::: "memory");
        else            asm volatile("s_waitcnt vmcnt(0)" ::: "memory");
        __builtin_amdgcn_s_barrier();
        __builtin_amdgcn_sched_barrier(0);
        if (t + 2 < nt) {
            int nb = buf + 2; if (nb >= 3) nb -= 3;
            STAGE(t + 2, nb);
        }
        bf16x8 af[4], bfr[4];
#pragma unroll
        for (int m = 0; m < 4; m++) {
            int row = wr * 64 + m * 16 + l15;
            af[m] = *(const bf16x8*)&sA[buf][row * 32 + ssr];
        }
#pragma unroll
        for (int n = 0; n < 4; n++) {
            int row = wc * 64 + n * 16 + l15;
            bfr[n] = *(const bf16x8*)&sB[buf][row * 32 + ssr];
        }
#pragma unroll
        for (int m = 0; m < 4; m++)
#pragma unroll
            for (int n = 0; n < 4; n++)
                acc[m][n] = __builtin_amdgcn_mfma_f32_16x16x32_bf16(af[m], bfr[n], acc[m][n], 0, 0, 0);
        buf = buf + 1; if (buf >= 3) buf = 0;
    }
#undef STAGE

    // ---- epilogue ----
    const int col0 = bn * 128 + wc * 64 + l15;
    float bias4[4];
#pragma unroll
    for (int nn = 0; nn < 4; nn++) bias4[nn] = bias[col0 + nn * 16];

#pragma unroll
    for (int m = 0; m < 4; m++) {
#pragma unroll
        for (int r = 0; r < 4; r++) {
            int row = bm * 256 + wr * 64 + m * 16 + (g << 2) + r;
            size_t obase;
            if (EPI == 1) {
                int win = row / NN, n = row - win * NN;
                int b_ = win >> 6, wi = win & 63;
                int hr = (wi >> 3) * 7 + n / 7;
                int wcl = (wi & 7) * 7 + n % 7;
                int hf = hr + 3; if (hf >= HH) hf -= HH;
                int wf = wcl + 3; if (wf >= WW) wf -= WW;
                obase = ((size_t)b_ * 3136 + hf * WW + wf) * DIM;
            } else {
                obase = (size_t)row * N;
            }
#pragma unroll
            for (int nn = 0; nn < 4; nn++) {
                int col = col0 + nn * 16;
                float val = acc[m][nn][r] + bias4[nn];
                if (EPI == 0) {
                    ((u16*)outp)[obase + col] = f2bf(val);
                } else if (EPI == 1) {
                    ((float*)outp)[obase + col] = val + resid[obase + col];
                } else if (EPI == 2) {
                    ((u16*)outp)[obase + col] = f2bf(fast_gelu(val));
                } else {
                    ((float*)outp)[obase + col] = val + resid[obase + col];
                }
            }
        }
    }
}

// ---------------- MFMA windowed attention: one wave per (window, head) -------
__global__ __launch_bounds__(256) void attn_kernel(
    const u16* __restrict__ qkv, const float* __restrict__ Tb,
    u16* __restrict__ attn_out)
{
    // per-wave LDS: Vt[32][72] + P[64][72] (u16), 13824 B/wave
    __shared__ u16 smem[4][6912];
    const int win = blockIdx.x;
    const int wave = threadIdx.x >> 6;
    const int lane = threadIdx.x & 63;
    const int head = blockIdx.y * 4 + wave;
    const int l15 = lane & 15, g = lane >> 4;

    u16* Vt = smem[wave];
    u16* P  = Vt + 2304;

    const u16* qkvw = qkv + (size_t)win * NN * 1152 + head * 32;

    // ---- stage V transposed (zero-pad rows >= 49) ----
    {
        int m = lane;
        bool real = m < NN;
        const u16* vrow = qkvw + (size_t)(real ? m : 0) * 1152 + 768;
        int4 z = {0,0,0,0};
        int4 c0 = real ? *(const int4*)(vrow)      : z;
        int4 c1 = real ? *(const int4*)(vrow + 8)  : z;
        int4 c2 = real ? *(const int4*)(vrow + 16) : z;
        int4 c3 = real ? *(const int4*)(vrow + 24) : z;
        u16 vals[32];
        *(int4*)&vals[0]  = c0; *(int4*)&vals[8]  = c1;
        *(int4*)&vals[16] = c2; *(int4*)&vals[24] = c3;
#pragma unroll
        for (int d = 0; d < 32; d++) Vt[d * 72 + m] = vals[d];
    }

    // ---- S^T = K * Q^T via MFMA (rows clamped to 48: no garbage) ----
    bf16x8 kf[4], qf[4];
#pragma unroll
    for (int t = 0; t < 4; t++) {
        int row = t * 16 + l15; if (row > 48) row = 48;
        const u16* base = qkvw + (size_t)row * 1152 + g * 8;
        kf[t] = *(const bf16x8*)(base + 384);
        qf[t] = *(const bf16x8*)(base);
    }
    f32x4 s[4][4];   // [key-tile mt][query-tile nt]
#pragma unroll
    for (int mt = 0; mt < 4; mt++)
#pragma unroll
        for (int nt = 0; nt < 4; nt++) {
            f32x4 zero = {};
            s[mt][nt] = __builtin_amdgcn_mfma_f32_16x16x32_bf16(kf[mt], qf[nt], zero, 0, 0, 0);
        }

    // ---- bias + mask + softmax (query = nt*16 + l15, keys in regs) ----
    const int wi = win & 63;
    const int ty = (((wi >> 3) == 7) ? 2 : 0) + (((wi & 7) == 7) ? 1 : 0);
    const float* tbb = Tb + (((size_t)ty * 12 + head) << 12);
    const float SCALE = 0.17677669529663687f;
#pragma unroll
    for (int nt = 0; nt < 4; nt++) {
        int q = nt * 16 + l15;
        const float* trow = tbb + q * 64 + g * 4;
        f32x4 b[4];
#pragma unroll
        for (int mt = 0; mt < 4; mt++) b[mt] = *(const f32x4*)(trow + mt * 16);
        float mx = -3e38f;
#pragma unroll
        for (int mt = 0; mt < 4; mt++)
#pragma unroll
            for (int r = 0; r < 4; r++) {
                float v = s[mt][nt][r] * SCALE + b[mt][r];
                s[mt][nt][r] = v;
                mx = fmaxf(mx, v);
            }
        mx = fmaxf(mx, __shfl_xor(mx, 16));
        mx = fmaxf(mx, __shfl_xor(mx, 32));
        float sum = 0.f;
#pragma unroll
        for (int mt = 0; mt < 4; mt++)
#pragma unroll
            for (int r = 0; r < 4; r++) {
                float e = __expf(s[mt][nt][r] - mx);
                s[mt][nt][r] = e;
                sum += e;
            }
        sum += __shfl_xor(sum, 16);
        sum += __shfl_xor(sum, 32);
        float inv = 1.f / sum;
#pragma unroll
        for (int mt = 0; mt < 4; mt++) {
            unsigned int p01 = (unsigned int)f2bf(s[mt][nt][0] * inv) | ((unsigned int)f2bf(s[mt][nt][1] * inv) << 16);
            unsigned int p23 = (unsigned int)f2bf(s[mt][nt][2] * inv) | ((unsigned int)f2bf(s[mt][nt][3] * inv) << 16);
            uint2 pk; pk.x = p01; pk.y = p23;
            *(uint2*)&P[(unsigned)q * 72 + mt * 16 + g * 4] = pk;
        }
    }

    // ---- O = P * V via MFMA ----
    bf16x8 vf[2][2];
#pragma unroll
    for (int ks = 0; ks < 2; ks++)
#pragma unroll
        for (int dt = 0; dt < 2; dt++)
            vf[ks][dt] = *(const bf16x8*)&Vt[(dt * 16 + l15) * 72 + ks * 32 + g * 8];

    f32x4 o[4][2] = {};
#pragma unroll
    for (int nt = 0; nt < 4; nt++) {
        bf16x8 pf0 = *(const bf16x8*)&P[(nt * 16 + l15) * 72 + g * 8];
        bf16x8 pf1 = *(const bf16x8*)&P[(nt * 16 + l15) * 72 + 32 + g * 8];
#pragma unroll
        for (int dt = 0; dt < 2; dt++) {
            o[nt][dt] = __builtin_amdgcn_mfma_f32_16x16x32_bf16(pf0, vf[0][dt], o[nt][dt], 0, 0, 0);
            o[nt][dt] = __builtin_amdgcn_mfma_f32_16x16x32_bf16(pf1, vf[1][dt], o[nt][dt], 0, 0, 0);
        }
    }

    // ---- write out ----
#pragma unroll
    for (int nt = 0; nt < 4; nt++)
#pragma unroll
        for (int r = 0; r < 4; r++) {
            int q = nt * 16 + 4 * g + r;
            if (q < NN) {
                size_t ob = ((size_t)win * NN + q) * DIM + head * 32;
                attn_out[ob + l15]      = f2bf(o[nt][0][r]);
                attn_out[ob + 16 + l15] = f2bf(o[nt][1][r]);
            }
        }
}

// ---------------- launch ------------------------------------------------------
extern "C" void kernel_launch(void* const* d_in, const int* in_sizes, int n_in,
                              void* d_out, int out_size, void* d_ws, size_t ws_size,
                              hipStream_t stream)
{
    const float* x      = (const float*)d_in[0];
    const float* qkv_w  = (const float*)d_in[1];
    const float* qkv_b  = (const float*)d_in[2];
    const float* proj_w = (const float*)d_in[3];
    const float* proj_b = (const float*)d_in[4];
    const float* rel_b  = (const float*)d_in[5];
    const float* n1w    = (const float*)d_in[6];
    const float* n1b    = (const float*)d_in[7];
    const float* n2w    = (const float*)d_in[8];
    const float* n2b    = (const float*)d_in[9];
    const float* w1     = (const float*)d_in[10];
    const float* b1     = (const float*)d_in[11];
    const float* w2     = (const float*)d_in[12];
    const float* b2     = (const float*)d_in[13];

    char* ws = (char*)d_ws;
    u16* hidden  = (u16*)(ws);                       // 100352x1536 bf16 (MLP hidden)
    u16* qkvbuf  = hidden;                           // 100352x1152 bf16 (aliases hidden)
    float* Tb    = (float*)(ws + 231211008);         // 4x12x64x64 f32 bias table
    u16* wxbuf   = (u16*)(ws + 308281344);           // 100352x384 bf16 (wx / attn_out / ln2)
    u16* qkv_wt  = (u16*)(ws + 385351680);           // 1152x384
    u16* proj_wt = (u16*)(ws + 386236416);           // 384x384
    u16* w1t     = (u16*)(ws + 386531328);           // 1536x384
    u16* w2t     = (u16*)(ws + 387710976);           // 384x1536

    castT<<<(1152*384 + 255) / 256, 256, 0, stream>>>(qkv_w, qkv_wt, 384, 1152);
    castT<<<(384*384  + 255) / 256, 256, 0, stream>>>(proj_w, proj_wt, 384, 384);
    castT<<<(384*1536 + 255) / 256, 256, 0, stream>>>(w1, w1t, 384, 1536);
    castT<<<(1536*384 + 255) / 256, 256, 0, stream>>>(w2, w2t, 1536, 384);
    bias_kernel<<<48, 256, 0, stream>>>(rel_b, Tb);

    // LN1 + roll + window partition (fwd write order)
    ln_kernel<true><<<NTOK / 4, 256, 0, stream>>>(x, n1w, n1b, wxbuf);
    // QKV GEMM — REV: writes qkvbuf per-chunk descending; attn (fwd) reads LIFO from L3
    gemm_kernel<0, true><<<392 * 9, 512, 0, stream>>>(wxbuf, qkv_wt, qkv_b, nullptr, qkvbuf, 1152, 384, 9);
    // attention (fwd)
    attn_kernel<<<dim3(NWIN, 3), 256, 0, stream>>>(qkvbuf, Tb, wxbuf);
    // proj GEMM + window reverse + roll + residual -> y1 (REV: ln2 fwd reads LIFO)
    gemm_kernel<1, true><<<392 * 3, 512, 0, stream>>>(wxbuf, proj_wt, proj_b, x, d_out, 384, 384, 3);
    // LN2 on y1 -> wxbuf (fwd)
    ln_kernel<false><<<NTOK / 4, 256, 0, stream>>>((const float*)d_out, n2w, n2b, wxbuf);
    // MLP1 + GELU -> hidden (REV: writes hidden descending; MLP2 fwd reads LIFO)
    gemm_kernel<2, true><<<392 * 12, 512, 0, stream>>>(wxbuf, w1t, b1, nullptr, hidden, 1536, 384, 12);
    // MLP2 + residual(y1) -> d_out (fwd)
    gemm_kernel<3, false><<<392 * 3, 512, 0, stream>>>(hidden, w2t, b2, (const float*)d_out, d_out, 384, 1536, 3);
}